// Round 14
// baseline (704.919 us; speedup 1.0000x reference)
//
#include <hip/hip_runtime.h>
#include <cstdint>
#include <cstddef>

#define T_ 512
#define B_ 128
#define D_ 256
#define H_ 512
#define C_ 10

typedef float  f32x4 __attribute__((ext_vector_type(4)));
typedef short  s16x8 __attribute__((ext_vector_type(8)));
typedef _Float16 v8h  __attribute__((ext_vector_type(8)));
typedef unsigned u32x8 __attribute__((ext_vector_type(8)));

static __device__ __forceinline__ unsigned short f2bf(float f) {
    unsigned u = __builtin_bit_cast(unsigned, f);
    unsigned r = u + 0x7FFFu + ((u >> 16) & 1u);
    return (unsigned short)(r >> 16);
}

// ---- fp8 e4m3fn encode (HW cvt if available, else software RNE) ----
static __device__ __forceinline__ unsigned char f2e4m3_sw(float f) {
    unsigned u = __builtin_bit_cast(unsigned, f);
    unsigned sgn = (u >> 24) & 0x80u;
    float a = fabsf(f);
    if (a != a) return (unsigned char)(sgn | 0x7E);
    if (a >= 448.0f) return (unsigned char)(sgn | 0x7E);
    if (a < 0.015625f) {
        int qv = (int)rintf(a * 512.0f);
        if (qv > 7) return (unsigned char)(sgn | 0x08);
        return (unsigned char)(sgn | qv);
    }
    unsigned ub = __builtin_bit_cast(unsigned, a);
    unsigned rr = ub + 0x7FFFFu + ((ub >> 20) & 1u);
    int E = (int)(rr >> 23) - 127 + 7;
    unsigned m = (rr >> 20) & 7u;
    if (E < 1)  { E = 0; m = 7; }
    if (E > 15) { E = 15; m = 6; }
    if (E == 15 && m == 7) m = 6;
    return (unsigned char)(sgn | ((unsigned)E << 3) | m);
}
template <bool HI>
static __device__ __forceinline__ unsigned cvt2_fp8(float a, float b, unsigned old) {
#if __has_builtin(__builtin_amdgcn_cvt_pk_fp8_f32)
    return (unsigned)__builtin_amdgcn_cvt_pk_fp8_f32(a, b, (int)old, HI);
#else
    unsigned p = (unsigned)f2e4m3_sw(a) | ((unsigned)f2e4m3_sw(b) << 8);
    return HI ? ((old & 0x0000FFFFu) | (p << 16)) : ((old & 0xFFFF0000u) | p);
#endif
}

static __device__ __forceinline__ float tanh_f(float x) {
    float ex = __expf(2.0f * x);
    return 1.0f - 2.0f * __builtin_amdgcn_rcpf(ex + 1.0f);
}

// ---------------------------------------------------------------------------
// k-permutation (shared by A-storage, B-fragments). K=512 = 4 chunks (s=0..3,
// chunk s produced by col-block W=s). Fragment slot (s, qa=lane>>4, ja=0..31)
// holds global k index:
//   c = 128*s + 64*(ja>>4) + 16*(ja&3) + 4*((ja>>2)&3) + qa        (bijection)
// LDS h-storage byte for (s, qa, ja, row m):
//   addr = s*2048 + qa*512 + (ja>>4)*256 + ((m ^ qa) * 16) + (ja & 15)
// ---------------------------------------------------------------------------

// ---------------------------------------------------------------------------
// Prep 0: W_hx [256,512] f32 -> W_hx^T [512,256] bf16
// ---------------------------------------------------------------------------
__global__ void k_whxT(const float* __restrict__ Whx, unsigned short* __restrict__ WhxT) {
    int idx = blockIdx.x * 256 + threadIdx.x;
    int n = idx >> 8;
    int k = idx & 255;
    WhxT[n * 256 + k] = f2bf(Whx[k * 512 + n]);
}

// ---------------------------------------------------------------------------
// Prep 1: W_hh f32 -> Wf8: fp8 e4m3 B-fragments for mfma 16x16x128 (k-permuted).
// ---------------------------------------------------------------------------
__global__ void k_wfrag8(const float* __restrict__ Whh, unsigned char* __restrict__ Wf8) {
    int gid = blockIdx.x * 256 + threadIdx.x;    // 8192 entries
    int l = gid & 63, grp = gid >> 6;
    int nb = grp & 7, s = (grp >> 3) & 3, Wt = grp >> 5;
    int col = 128 * Wt + 16 * nb + (l & 15);
    int qa = l >> 4;
    unsigned dw[8];
#pragma unroll
    for (int d = 0; d < 8; ++d) {
        float vv[4];
#pragma unroll
        for (int b = 0; b < 4; ++b) {
            int j = d * 4 + b;
            int c = 128 * s + 64 * (j >> 4) + 16 * (j & 3) + 4 * ((j >> 2) & 3) + qa;
            vv[b] = Whh[(size_t)c * 512 + col];
        }
        unsigned p = cvt2_fp8<false>(vv[0], vv[1], 0u);
        dw[d] = cvt2_fp8<true>(vv[2], vv[3], p);
    }
    u32x8 out;
#pragma unroll
    for (int d = 0; d < 8; ++d) out[d] = dw[d];
    *((u32x8*)Wf8 + gid) = out;
}

// ---------------------------------------------------------------------------
// Phase 1: Z = x @ W_hx + b_h, written in k_rnn's Zr layout.
// ---------------------------------------------------------------------------
__global__ void __launch_bounds__(256) k_gemm1(const float* __restrict__ x,
                                               const unsigned short* __restrict__ WhxT,
                                               const float* __restrict__ bh,
                                               char* __restrict__ Zr) {
    __shared__ char smem[32768];
    unsigned short* Asm = (unsigned short*)smem;
    unsigned short* Bsm = (unsigned short*)(smem + 8192);

    const int tid = threadIdx.x;
    const int bid = blockIdx.x;
    const int nt = bid & 3, mt = bid >> 2;
    const int r0 = mt * 128, n0 = nt * 128;
    const int w  = tid >> 6, l = tid & 63;
    const int wm = (w >> 1) * 64, wn = (w & 1) * 64;
    const int lr = l & 15, lk = (l >> 4) * 8;

    const int arow = tid >> 2, akc = (tid & 3) * 8;
    const int bcol = tid >> 1, bkc = (tid & 1) * 16;

    f32x4 acc[4][4] = {};

    for (int kk = 0; kk < 256; kk += 32) {
#pragma unroll
        for (int half = 0; half < 2; ++half) {
            const int r = arow + half * 64;
            const float* ap = x + (size_t)(r0 + r) * 256 + kk + akc;
            float4 f0 = *(const float4*)ap;
            float4 f1 = *(const float4*)(ap + 4);
            uint4 av;
            av.x = (unsigned)f2bf(f0.x) | ((unsigned)f2bf(f0.y) << 16);
            av.y = (unsigned)f2bf(f0.z) | ((unsigned)f2bf(f0.w) << 16);
            av.z = (unsigned)f2bf(f1.x) | ((unsigned)f2bf(f1.y) << 16);
            av.w = (unsigned)f2bf(f1.z) | ((unsigned)f2bf(f1.w) << 16);
            *(uint4*)&Asm[r * 32 + akc] = av;
        }
        const unsigned short* bsrc = WhxT + (size_t)(n0 + bcol) * 256 + kk + bkc;
        uint4 bv0 = *(const uint4*)bsrc;
        uint4 bv1 = *(const uint4*)(bsrc + 8);
        *(uint4*)&Bsm[bcol * 32 + bkc] = bv0;
        *(uint4*)&Bsm[bcol * 32 + bkc + 8] = bv1;
        __syncthreads();

        s16x8 af[4], bf[4];
#pragma unroll
        for (int mi = 0; mi < 4; ++mi)
            af[mi] = *(const s16x8*)&Asm[(wm + mi * 16 + lr) * 32 + lk];
#pragma unroll
        for (int ni = 0; ni < 4; ++ni)
            bf[ni] = *(const s16x8*)&Bsm[(wn + ni * 16 + lr) * 32 + lk];
#pragma unroll
        for (int mi = 0; mi < 4; ++mi)
#pragma unroll
            for (int ni = 0; ni < 4; ++ni)
                acc[mi][ni] = __builtin_amdgcn_mfma_f32_16x16x32_bf16(af[mi], bf[ni], acc[mi][ni], 0, 0, 0);
        __syncthreads();
    }

    _Float16* Szr = (_Float16*)smem;   // [cu][g][m][q] = 32 KiB
#pragma unroll
    for (int mi = 0; mi < 4; ++mi)
#pragma unroll
        for (int ni = 0; ni < 4; ++ni) {
            const int col_l = wn + ni * 16 + lr;
            const float bhv = bh[n0 + col_l];
            const int g   = (col_l >> 5) & 3;
            const int qhi = ((col_l >> 4) & 1) * 4;
#pragma unroll
            for (int e = 0; e < 4; ++e) {
                const int b   = wm + mi * 16 + (l >> 4) * 4 + e;
                const int cu  = b >> 4;
                const int m_r = ((b & 15) >> 2) * 16 + lr;
                Szr[((cu * 4 + g) * 64 + m_r) * 8 + qhi + e] = (_Float16)(acc[mi][ni][e] + bhv);
            }
        }
    __syncthreads();
    {
        const uint4* srcv = (const uint4*)smem;
#pragma unroll
        for (int i = 0; i < 8; ++i) {
            const int o   = tid * 128 + i * 16;
            const int cuo = o >> 12;
            char* dst = Zr + ((size_t)((mt * 8 + cuo) * 4 + nt)) * 4096 + (o & 4095);
            *(uint4*)dst = srcv[o >> 4];
        }
    }
}

// ---------------------------------------------------------------------------
// Phase 2: fp8 K=128 MFMA recurrence, chain-major pipelined. 8 WGs x 512
// threads (8 waves, 2/SIMD). Step = 4 sub-blocks of [4 back-to-back chained
// MFMAs on one accumulator], pinned with sched_barrier, then per-accumulator
// epilogues: cc0 completes at chain latency (~150-270cy), its tanh epilogue
// runs while chains 1-3 still occupy the matrix pipe -> MFMA/VALU overlap.
// ---------------------------------------------------------------------------
#define MM128(C_, A_, B_) \
    asm("v_mfma_f32_16x16x128_f8f6f4 %0, %1, %2, %0" : "+v"(C_) : "v"(A_), "a"(B_))
#define SB0() __builtin_amdgcn_sched_barrier(0)
#define WALL48() do { SB0(); \
    asm volatile("s_nop 7\n\ts_nop 7\n\ts_nop 7\n\ts_nop 7\n\ts_nop 7\n\ts_nop 7" ::); \
    SB0(); } while (0)
#define WALL16() do { SB0(); asm volatile("s_nop 7\n\ts_nop 7" ::); SB0(); } while (0)

__global__
__attribute__((amdgpu_flat_work_group_size(512, 512), amdgpu_waves_per_eu(2, 2)))
void k_rnn(const unsigned char* __restrict__ Wf8,
           const char* __restrict__ Zr,
           float* __restrict__ hf) {
    __shared__ char hA[2][8192];   // h as fp8 A-fragments, double-buffered

    const int tid = threadIdx.x, cu = blockIdx.x;
    const int w8 = tid >> 6;          // wave 0..7
    const int W  = w8 >> 1;           // col block 0..3 == k-chunk it produces
    const int hf4 = w8 & 1;           // nb half
    const int l = tid & 63;
    const int r = l & 15, q = l >> 4;

    // ---- stationary B: 4 chunks x 4 nb tiles x 8 regs -> 128 AGPRs ----
    u32x8 BA[4][4];
    {
        const u32x8* Wb = (const u32x8*)Wf8;
#pragma unroll
        for (int s = 0; s < 4; ++s)
#pragma unroll
            for (int jn = 0; jn < 4; ++jn)
                BA[s][jn] = Wb[(size_t)(((W * 4 + s) * 8) + 4 * hf4 + jn) * 64 + l];
    }

    // h0 = 0 (both buffers)
    ((uint4*)hA)[tid]       = uint4{0, 0, 0, 0};
    ((uint4*)hA)[512 + tid] = uint4{0, 0, 0, 0};
    __syncthreads();

    // per-thread invariant offsets
    const int qa = r & 3, rq = r >> 2;
    int rdo[4][2];                     // read: [chunk s][half]
#pragma unroll
    for (int s = 0; s < 4; ++s) {
        rdo[s][0] = s * 2048 + q * 512 + ((r ^ q) << 4);
        rdo[s][1] = rdo[s][0] + 256;
    }
    int wd[4];                         // write: [e] (bytes jn0,1 at +0; jn2,3 at +2)
#pragma unroll
    for (int e = 0; e < 4; ++e)
        wd[e] = W * 2048 + qa * 512 + hf4 * 256 + (((4 * q + e) ^ qa) << 4) + 4 * rq;

    // z pointers (incremental; stride per t = 8*4*4096 B)
    const char* zp = Zr + ((size_t)cu * 4 + W) * 4096 + (size_t)(2 * hf4) * 1024 + (size_t)l * 16;
    v8h zl0 = *(const v8h*)zp;
    v8h zl1 = *(const v8h*)(zp + 1024);

    for (int t = 0; t < T_; ++t) {
        char* rb = &hA[t & 1][0];
        char* ob = &hA[(t & 1) ^ 1][0];

        // A fragments: 8 x ds_read_b128 (bank-uniform)
        u32x8 av[4];
#pragma unroll
        for (int s = 0; s < 4; ++s) {
            uint4 lo = *(const uint4*)(rb + rdo[s][0]);
            uint4 hi = *(const uint4*)(rb + rdo[s][1]);
            av[s][0] = lo.x; av[s][1] = lo.y; av[s][2] = lo.z; av[s][3] = lo.w;
            av[s][4] = hi.x; av[s][5] = hi.y; av[s][6] = hi.z; av[s][7] = hi.w;
        }

        // prefetch z for t+1
        const char* zq = (t + 1 < T_) ? zp + 131072 : zp;
        v8h zn0 = *(const v8h*)zq;
        v8h zn1 = *(const v8h*)(zq + 1024);
        zp = zq;

        // ---- 4 chain-major MFMA sub-blocks (each: 4 back-to-back chained) ----
        f32x4 cc0, cc1, cc2, cc3;
#pragma unroll
        for (int e = 0; e < 4; ++e) cc0[e] = (float)zl0[e];
        MM128(cc0, av[0], BA[0][0]); MM128(cc0, av[1], BA[1][0]);
        MM128(cc0, av[2], BA[2][0]); MM128(cc0, av[3], BA[3][0]);
        SB0();
#pragma unroll
        for (int e = 0; e < 4; ++e) cc1[e] = (float)zl0[4 + e];
        MM128(cc1, av[0], BA[0][1]); MM128(cc1, av[1], BA[1][1]);
        MM128(cc1, av[2], BA[2][1]); MM128(cc1, av[3], BA[3][1]);
        SB0();
#pragma unroll
        for (int e = 0; e < 4; ++e) cc2[e] = (float)zl1[e];
        MM128(cc2, av[0], BA[0][2]); MM128(cc2, av[1], BA[1][2]);
        MM128(cc2, av[2], BA[2][2]); MM128(cc2, av[3], BA[3][2]);
        SB0();
#pragma unroll
        for (int e = 0; e < 4; ++e) cc3[e] = (float)zl1[4 + e];
        MM128(cc3, av[0], BA[0][3]); MM128(cc3, av[1], BA[1][3]);
        MM128(cc3, av[2], BA[2][3]); MM128(cc3, av[3], BA[3][3]);

        // ---- epilogues, overlapping the later chains' execution ----
        WALL48();
        float h0[4];
#pragma unroll
        for (int e = 0; e < 4; ++e) h0[e] = tanh_f(cc0[e]);

        WALL16();
#pragma unroll
        for (int e = 0; e < 4; ++e) {
            float h1 = tanh_f(cc1[e]);
            unsigned p = cvt2_fp8<false>(h0[e], h1, 0u);
            *(unsigned short*)(ob + wd[e]) = (unsigned short)p;
            if (t == T_ - 1) {
                size_t row = (size_t)(16 * cu + 4 * q + e) * 512 + 128 * W + 64 * hf4 + r;
                hf[row + 0]  = h0[e]; hf[row + 16] = h1;
            }
        }

        WALL16();
        float h2[4];
#pragma unroll
        for (int e = 0; e < 4; ++e) h2[e] = tanh_f(cc2[e]);

        WALL16();
#pragma unroll
        for (int e = 0; e < 4; ++e) {
            float h3 = tanh_f(cc3[e]);
            unsigned p = cvt2_fp8<false>(h2[e], h3, 0u);
            *(unsigned short*)(ob + wd[e] + 2) = (unsigned short)p;
            if (t == T_ - 1) {
                size_t row = (size_t)(16 * cu + 4 * q + e) * 512 + 128 * W + 64 * hf4 + r;
                hf[row + 32] = h2[e]; hf[row + 48] = h3;
            }
        }

        zl0 = zn0; zl1 = zn1;
        __syncthreads();
    }
}

// ---------------------------------------------------------------------------
// Phase 3: out = h_final @ W_ph + b_p   [128,512]@[512,10]
// ---------------------------------------------------------------------------
__global__ void k_out(const float* __restrict__ hf, const float* __restrict__ Wph,
                      const float* __restrict__ bp, float* __restrict__ out) {
    __shared__ float red[160];
    int b = blockIdx.x, t = threadIdx.x;
    if (t < 160) {
        int c = t >> 4, ks = (t & 15) * 32;
        float s = 0.f;
        for (int u = 0; u < 32; ++u)
            s += hf[b * H_ + ks + u] * Wph[(ks + u) * C_ + c];
        red[t] = s;
    }
    __syncthreads();
    if (t < C_) {
        float s = bp[t];
        for (int i = 0; i < 16; ++i) s += red[t * 16 + i];
        out[b * C_ + t] = s;
    }
}

// ---------------------------------------------------------------------------
extern "C" void kernel_launch(void* const* d_in, const int* in_sizes, int n_in,
                              void* d_out, int out_size, void* d_ws, size_t ws_size,
                              hipStream_t stream) {
    const float* x   = (const float*)d_in[0];   // [512,128,256]
    const float* Whx = (const float*)d_in[1];   // [256,512]
    const float* Whh = (const float*)d_in[2];   // [512,512]
    const float* Wph = (const float*)d_in[3];   // [512,10]
    const float* bh  = (const float*)d_in[4];   // [512]
    const float* bp  = (const float*)d_in[5];   // [10]
    float* out = (float*)d_out;                 // [128,10] f32

    char* ws = (char*)d_ws;
    unsigned short* WhxT = (unsigned short*)(ws);                    // 256 KiB
    unsigned char*  Wf8  = (unsigned char*)(ws + 262144);            // 256 KiB
    char*           Zr   = ws + 786432;                              // 64 MiB
    float*          hf   = (float*)(ws + 786432 + 67108864);         // 256 KiB

    hipLaunchKernelGGL(k_whxT,   dim3(512),  dim3(256), 0, stream, Whx, WhxT);
    hipLaunchKernelGGL(k_wfrag8, dim3(32),   dim3(256), 0, stream, Whh, Wf8);
    hipLaunchKernelGGL(k_gemm1,  dim3(2048), dim3(256), 0, stream, x, WhxT, bh, Zr);
    hipLaunchKernelGGL(k_rnn,    dim3(8),    dim3(512), 0, stream, Wf8, Zr, hf);
    hipLaunchKernelGGL(k_out,    dim3(128),  dim3(256), 0, stream, hf, Wph, bp, out);
}

// Round 15
// 607.570 us; speedup vs baseline: 1.1602x; 1.1602x over previous
//
#include <hip/hip_runtime.h>
#include <cstdint>
#include <cstddef>

#define T_ 512
#define B_ 128
#define D_ 256
#define H_ 512
#define C_ 10

typedef float  f32x4 __attribute__((ext_vector_type(4)));
typedef short  s16x8 __attribute__((ext_vector_type(8)));
typedef _Float16 v8h  __attribute__((ext_vector_type(8)));
typedef unsigned u32x8 __attribute__((ext_vector_type(8)));

static __device__ __forceinline__ unsigned short f2bf(float f) {
    unsigned u = __builtin_bit_cast(unsigned, f);
    unsigned r = u + 0x7FFFu + ((u >> 16) & 1u);
    return (unsigned short)(r >> 16);
}

// ---- fp8 e4m3fn encode (HW cvt if available, else software RNE) ----
static __device__ __forceinline__ unsigned char f2e4m3_sw(float f) {
    unsigned u = __builtin_bit_cast(unsigned, f);
    unsigned sgn = (u >> 24) & 0x80u;
    float a = fabsf(f);
    if (a != a) return (unsigned char)(sgn | 0x7E);
    if (a >= 448.0f) return (unsigned char)(sgn | 0x7E);
    if (a < 0.015625f) {
        int qv = (int)rintf(a * 512.0f);
        if (qv > 7) return (unsigned char)(sgn | 0x08);
        return (unsigned char)(sgn | qv);
    }
    unsigned ub = __builtin_bit_cast(unsigned, a);
    unsigned rr = ub + 0x7FFFFu + ((ub >> 20) & 1u);
    int E = (int)(rr >> 23) - 127 + 7;
    unsigned m = (rr >> 20) & 7u;
    if (E < 1)  { E = 0; m = 7; }
    if (E > 15) { E = 15; m = 6; }
    if (E == 15 && m == 7) m = 6;
    return (unsigned char)(sgn | ((unsigned)E << 3) | m);
}
template <bool HI>
static __device__ __forceinline__ unsigned cvt2_fp8(float a, float b, unsigned old) {
#if __has_builtin(__builtin_amdgcn_cvt_pk_fp8_f32)
    return (unsigned)__builtin_amdgcn_cvt_pk_fp8_f32(a, b, (int)old, HI);
#else
    unsigned p = (unsigned)f2e4m3_sw(a) | ((unsigned)f2e4m3_sw(b) << 8);
    return HI ? ((old & 0x0000FFFFu) | (p << 16)) : ((old & 0xFFFF0000u) | p);
#endif
}

static __device__ __forceinline__ float tanh_f(float x) {
#if __has_builtin(__builtin_amdgcn_exp2f)
    float ex = __builtin_amdgcn_exp2f(2.885390081777927f * x);   // e^{2x}
#else
    float ex = __expf(2.0f * x);
#endif
    return 1.0f - 2.0f * __builtin_amdgcn_rcpf(ex + 1.0f);
}

// ---------------------------------------------------------------------------
// k-permutation (shared by A-storage, B-fragments). K=512 = 4 chunks (s=0..3,
// chunk s produced by col-block W=s). Fragment slot (s, qa=lane>>4, ja=0..31)
// holds global k index:
//   c = 128*s + 64*(ja>>4) + 16*(ja&3) + 4*((ja>>2)&3) + qa        (bijection)
// LDS h-storage byte for (s, qa, ja, row m):
//   addr = s*2048 + qa*512 + (ja>>4)*256 + ((m ^ qa) * 16) + (ja & 15)
// ---------------------------------------------------------------------------

// ---------------------------------------------------------------------------
// Prep 0: W_hx [256,512] f32 -> W_hx^T [512,256] bf16
// ---------------------------------------------------------------------------
__global__ void k_whxT(const float* __restrict__ Whx, unsigned short* __restrict__ WhxT) {
    int idx = blockIdx.x * 256 + threadIdx.x;
    int n = idx >> 8;
    int k = idx & 255;
    WhxT[n * 256 + k] = f2bf(Whx[k * 512 + n]);
}

// ---------------------------------------------------------------------------
// Prep 1: W_hh f32 -> Wf8: fp8 e4m3 B-fragments for mfma 16x16x128 (k-permuted).
// ---------------------------------------------------------------------------
__global__ void k_wfrag8(const float* __restrict__ Whh, unsigned char* __restrict__ Wf8) {
    int gid = blockIdx.x * 256 + threadIdx.x;    // 8192 entries
    int l = gid & 63, grp = gid >> 6;
    int nb = grp & 7, s = (grp >> 3) & 3, Wt = grp >> 5;
    int col = 128 * Wt + 16 * nb + (l & 15);
    int qa = l >> 4;
    unsigned dw[8];
#pragma unroll
    for (int d = 0; d < 8; ++d) {
        float vv[4];
#pragma unroll
        for (int b = 0; b < 4; ++b) {
            int j = d * 4 + b;
            int c = 128 * s + 64 * (j >> 4) + 16 * (j & 3) + 4 * ((j >> 2) & 3) + qa;
            vv[b] = Whh[(size_t)c * 512 + col];
        }
        unsigned p = cvt2_fp8<false>(vv[0], vv[1], 0u);
        dw[d] = cvt2_fp8<true>(vv[2], vv[3], p);
    }
    u32x8 out;
#pragma unroll
    for (int d = 0; d < 8; ++d) out[d] = dw[d];
    *((u32x8*)Wf8 + gid) = out;
}

// ---------------------------------------------------------------------------
// Phase 1: Z = x @ W_hx + b_h, written in k_rnn's Zr layout.
// ---------------------------------------------------------------------------
__global__ void __launch_bounds__(256) k_gemm1(const float* __restrict__ x,
                                               const unsigned short* __restrict__ WhxT,
                                               const float* __restrict__ bh,
                                               char* __restrict__ Zr) {
    __shared__ char smem[32768];
    unsigned short* Asm = (unsigned short*)smem;
    unsigned short* Bsm = (unsigned short*)(smem + 8192);

    const int tid = threadIdx.x;
    const int bid = blockIdx.x;
    const int nt = bid & 3, mt = bid >> 2;
    const int r0 = mt * 128, n0 = nt * 128;
    const int w  = tid >> 6, l = tid & 63;
    const int wm = (w >> 1) * 64, wn = (w & 1) * 64;
    const int lr = l & 15, lk = (l >> 4) * 8;

    const int arow = tid >> 2, akc = (tid & 3) * 8;
    const int bcol = tid >> 1, bkc = (tid & 1) * 16;

    f32x4 acc[4][4] = {};

    for (int kk = 0; kk < 256; kk += 32) {
#pragma unroll
        for (int half = 0; half < 2; ++half) {
            const int r = arow + half * 64;
            const float* ap = x + (size_t)(r0 + r) * 256 + kk + akc;
            float4 f0 = *(const float4*)ap;
            float4 f1 = *(const float4*)(ap + 4);
            uint4 av;
            av.x = (unsigned)f2bf(f0.x) | ((unsigned)f2bf(f0.y) << 16);
            av.y = (unsigned)f2bf(f0.z) | ((unsigned)f2bf(f0.w) << 16);
            av.z = (unsigned)f2bf(f1.x) | ((unsigned)f2bf(f1.y) << 16);
            av.w = (unsigned)f2bf(f1.z) | ((unsigned)f2bf(f1.w) << 16);
            *(uint4*)&Asm[r * 32 + akc] = av;
        }
        const unsigned short* bsrc = WhxT + (size_t)(n0 + bcol) * 256 + kk + bkc;
        uint4 bv0 = *(const uint4*)bsrc;
        uint4 bv1 = *(const uint4*)(bsrc + 8);
        *(uint4*)&Bsm[bcol * 32 + bkc] = bv0;
        *(uint4*)&Bsm[bcol * 32 + bkc + 8] = bv1;
        __syncthreads();

        s16x8 af[4], bf[4];
#pragma unroll
        for (int mi = 0; mi < 4; ++mi)
            af[mi] = *(const s16x8*)&Asm[(wm + mi * 16 + lr) * 32 + lk];
#pragma unroll
        for (int ni = 0; ni < 4; ++ni)
            bf[ni] = *(const s16x8*)&Bsm[(wn + ni * 16 + lr) * 32 + lk];
#pragma unroll
        for (int mi = 0; mi < 4; ++mi)
#pragma unroll
            for (int ni = 0; ni < 4; ++ni)
                acc[mi][ni] = __builtin_amdgcn_mfma_f32_16x16x32_bf16(af[mi], bf[ni], acc[mi][ni], 0, 0, 0);
        __syncthreads();
    }

    _Float16* Szr = (_Float16*)smem;   // [cu][g][m][q] = 32 KiB
#pragma unroll
    for (int mi = 0; mi < 4; ++mi)
#pragma unroll
        for (int ni = 0; ni < 4; ++ni) {
            const int col_l = wn + ni * 16 + lr;
            const float bhv = bh[n0 + col_l];
            const int g   = (col_l >> 5) & 3;
            const int qhi = ((col_l >> 4) & 1) * 4;
#pragma unroll
            for (int e = 0; e < 4; ++e) {
                const int b   = wm + mi * 16 + (l >> 4) * 4 + e;
                const int cu  = b >> 4;
                const int m_r = ((b & 15) >> 2) * 16 + lr;
                Szr[((cu * 4 + g) * 64 + m_r) * 8 + qhi + e] = (_Float16)(acc[mi][ni][e] + bhv);
            }
        }
    __syncthreads();
    {
        const uint4* srcv = (const uint4*)smem;
#pragma unroll
        for (int i = 0; i < 8; ++i) {
            const int o   = tid * 128 + i * 16;
            const int cuo = o >> 12;
            char* dst = Zr + ((size_t)((mt * 8 + cuo) * 4 + nt)) * 4096 + (o & 4095);
            *(uint4*)dst = srcv[o >> 4];
        }
    }
}

// ---------------------------------------------------------------------------
// Phase 2: fp8 K=128 MFMA recurrence, pair-pipelined (round-13 structure) +
// wave-asymmetric s_setprio stagger. Waves 0-3 (one per SIMD; partner wave is
// w8+4) raise prio to 1 during their MFMA bursts only -> their MFMAs drain
// the matrix pipe first, and their epilogue VALU overlaps the partner wave's
// deferred MFMA burst (true MFMA||VALU overlap across waves).
// ---------------------------------------------------------------------------
#define MM128(C_, A_, B_) \
    asm("v_mfma_f32_16x16x128_f8f6f4 %0, %1, %2, %0" : "+v"(C_) : "v"(A_), "a"(B_))

__global__
__attribute__((amdgpu_flat_work_group_size(512, 512), amdgpu_waves_per_eu(2, 2)))
void k_rnn(const unsigned char* __restrict__ Wf8,
           const char* __restrict__ Zr,
           float* __restrict__ hf) {
    __shared__ char hA[2][8192];   // h as fp8 A-fragments, double-buffered

    const int tid = threadIdx.x, cu = blockIdx.x;
    const int w8 = tid >> 6;          // wave 0..7
    const int W  = w8 >> 1;           // col block 0..3 == k-chunk it produces
    const int hf4 = w8 & 1;           // nb half
    const int l = tid & 63;
    const int r = l & 15, q = l >> 4;
    const bool lead = (w8 < 4);       // SIMD s hosts waves s and s+4

    // ---- stationary B: 4 chunks x 4 nb tiles x 8 regs -> 128 AGPRs ----
    u32x8 BA[4][4];
    {
        const u32x8* Wb = (const u32x8*)Wf8;
#pragma unroll
        for (int s = 0; s < 4; ++s)
#pragma unroll
            for (int jn = 0; jn < 4; ++jn)
                BA[s][jn] = Wb[(size_t)(((W * 4 + s) * 8) + 4 * hf4 + jn) * 64 + l];
    }

    // h0 = 0 (both buffers)
    ((uint4*)hA)[tid]       = uint4{0, 0, 0, 0};
    ((uint4*)hA)[512 + tid] = uint4{0, 0, 0, 0};
    __syncthreads();

    // per-thread invariant offsets
    const int qa = r & 3, rq = r >> 2;
    int rdo[4][2];                     // read: [chunk s][half]
#pragma unroll
    for (int s = 0; s < 4; ++s) {
        rdo[s][0] = s * 2048 + q * 512 + ((r ^ q) << 4);
        rdo[s][1] = rdo[s][0] + 256;
    }
    int wd[4];                         // write: [e] (bytes jn0,1 at +0; jn2,3 at +2)
#pragma unroll
    for (int e = 0; e < 4; ++e)
        wd[e] = W * 2048 + qa * 512 + hf4 * 256 + (((4 * q + e) ^ qa) << 4) + 4 * rq;

    // z pointers (incremental; stride per t = 8*4*4096 B)
    const char* zp = Zr + ((size_t)cu * 4 + W) * 4096 + (size_t)(2 * hf4) * 1024 + (size_t)l * 16;
    v8h zl0 = *(const v8h*)zp;
    v8h zl1 = *(const v8h*)(zp + 1024);

    for (int t = 0; t < T_; ++t) {
        char* rb = &hA[t & 1][0];
        char* ob = &hA[(t & 1) ^ 1][0];

        // A fragments: 8 x ds_read_b128 (bank-uniform)
        u32x8 av[4];
#pragma unroll
        for (int s = 0; s < 4; ++s) {
            uint4 lo = *(const uint4*)(rb + rdo[s][0]);
            uint4 hi = *(const uint4*)(rb + rdo[s][1]);
            av[s][0] = lo.x; av[s][1] = lo.y; av[s][2] = lo.z; av[s][3] = lo.w;
            av[s][4] = hi.x; av[s][5] = hi.y; av[s][6] = hi.z; av[s][7] = hi.w;
        }

        // prefetch z for t+1
        const char* zq = (t + 1 < T_) ? zp + 131072 : zp;
        v8h zn0 = *(const v8h*)zq;
        v8h zn1 = *(const v8h*)(zq + 1024);
        zp = zq;

        // ================= pair 0: jn = 0,1 (z-initialized C) =================
        f32x4 cc0, cc1;
#pragma unroll
        for (int e = 0; e < 4; ++e) {
            cc0[e] = (float)zl0[e];
            cc1[e] = (float)zl0[4 + e];
        }
        if (lead) __builtin_amdgcn_s_setprio(1);
#pragma unroll
        for (int s = 0; s < 4; ++s) {
            MM128(cc0, av[s], BA[s][0]);
            MM128(cc1, av[s], BA[s][1]);
        }
        if (lead) __builtin_amdgcn_s_setprio(0);
        __builtin_amdgcn_sched_barrier(0);
        asm volatile("s_nop 7\n\ts_nop 7\n\ts_nop 7\n\ts_nop 7\n\ts_nop 7\n\ts_nop 7" ::);
        __builtin_amdgcn_sched_barrier(0);
#pragma unroll
        for (int e = 0; e < 4; ++e) {
            float h0 = tanh_f(cc0[e]);
            float h1 = tanh_f(cc1[e]);
            unsigned p = cvt2_fp8<false>(h0, h1, 0u);
            *(unsigned short*)(ob + wd[e]) = (unsigned short)p;
            if (t == T_ - 1) {
                size_t row = (size_t)(16 * cu + 4 * q + e) * 512 + 128 * W + 64 * hf4 + r;
                hf[row + 0]  = h0; hf[row + 16] = h1;
            }
        }

        // ================= pair 1: jn = 2,3 =================
        f32x4 cc2, cc3;
#pragma unroll
        for (int e = 0; e < 4; ++e) {
            cc2[e] = (float)zl1[e];
            cc3[e] = (float)zl1[4 + e];
        }
        if (lead) __builtin_amdgcn_s_setprio(1);
#pragma unroll
        for (int s = 0; s < 4; ++s) {
            MM128(cc2, av[s], BA[s][2]);
            MM128(cc3, av[s], BA[s][3]);
        }
        if (lead) __builtin_amdgcn_s_setprio(0);
        __builtin_amdgcn_sched_barrier(0);
        asm volatile("s_nop 7\n\ts_nop 7\n\ts_nop 7\n\ts_nop 7\n\ts_nop 7\n\ts_nop 7" ::);
        __builtin_amdgcn_sched_barrier(0);
#pragma unroll
        for (int e = 0; e < 4; ++e) {
            float h2 = tanh_f(cc2[e]);
            float h3 = tanh_f(cc3[e]);
            unsigned p = cvt2_fp8<false>(h2, h3, 0u);
            *(unsigned short*)(ob + wd[e] + 2) = (unsigned short)p;
            if (t == T_ - 1) {
                size_t row = (size_t)(16 * cu + 4 * q + e) * 512 + 128 * W + 64 * hf4 + r;
                hf[row + 32] = h2; hf[row + 48] = h3;
            }
        }

        zl0 = zn0; zl1 = zn1;
        __syncthreads();
    }
}

// ---------------------------------------------------------------------------
// Phase 3: out = h_final @ W_ph + b_p   [128,512]@[512,10]
// ---------------------------------------------------------------------------
__global__ void k_out(const float* __restrict__ hf, const float* __restrict__ Wph,
                      const float* __restrict__ bp, float* __restrict__ out) {
    __shared__ float red[160];
    int b = blockIdx.x, t = threadIdx.x;
    if (t < 160) {
        int c = t >> 4, ks = (t & 15) * 32;
        float s = 0.f;
        for (int u = 0; u < 32; ++u)
            s += hf[b * H_ + ks + u] * Wph[(ks + u) * C_ + c];
        red[t] = s;
    }
    __syncthreads();
    if (t < C_) {
        float s = bp[t];
        for (int i = 0; i < 16; ++i) s += red[t * 16 + i];
        out[b * C_ + t] = s;
    }
}

// ---------------------------------------------------------------------------
extern "C" void kernel_launch(void* const* d_in, const int* in_sizes, int n_in,
                              void* d_out, int out_size, void* d_ws, size_t ws_size,
                              hipStream_t stream) {
    const float* x   = (const float*)d_in[0];   // [512,128,256]
    const float* Whx = (const float*)d_in[1];   // [256,512]
    const float* Whh = (const float*)d_in[2];   // [512,512]
    const float* Wph = (const float*)d_in[3];   // [512,10]
    const float* bh  = (const float*)d_in[4];   // [512]
    const float* bp  = (const float*)d_in[5];   // [10]
    float* out = (float*)d_out;                 // [128,10] f32

    char* ws = (char*)d_ws;
    unsigned short* WhxT = (unsigned short*)(ws);                    // 256 KiB
    unsigned char*  Wf8  = (unsigned char*)(ws + 262144);            // 256 KiB
    char*           Zr   = ws + 786432;                              // 64 MiB
    float*          hf   = (float*)(ws + 786432 + 67108864);         // 256 KiB

    hipLaunchKernelGGL(k_whxT,   dim3(512),  dim3(256), 0, stream, Whx, WhxT);
    hipLaunchKernelGGL(k_wfrag8, dim3(32),   dim3(256), 0, stream, Whh, Wf8);
    hipLaunchKernelGGL(k_gemm1,  dim3(2048), dim3(256), 0, stream, x, WhxT, bh, Zr);
    hipLaunchKernelGGL(k_rnn,    dim3(8),    dim3(512), 0, stream, Wf8, Zr, hf);
    hipLaunchKernelGGL(k_out,    dim3(128),  dim3(256), 0, stream, hf, Wph, bp, out);
}